// Round 9
// baseline (529.437 us; speedup 1.0000x reference)
//
#include <hip/hip_runtime.h>
#include <hip/hip_bf16.h>
#include <math.h>

#define N_NODES 50000
#define N_EDGES 800000
#define NFEAT   512
#define HID     96
#define NCLASS  64
#define NUM_LAYERS 8
#define ALPHA   0.1f
#define NSB     49          // scan blocks: ceil(50000/1024)
#define NBB     196         // bin blocks: ceil(50000/256)
// source-range split for L2 phase locality: 3 ranges x ~16.7k rows (~3.2MB of h each,
// fits the 4MB per-XCD L2). CSR rows store sources grouped by range.
#define R1      16667
#define R2      33334

typedef __attribute__((ext_vector_type(8))) short short8;
typedef __attribute__((ext_vector_type(4))) float f32x4;

__device__ __forceinline__ unsigned short f2bf(float f) {
    unsigned int u = __float_as_uint(f);
    unsigned int r = u + 0x7FFF + ((u >> 16) & 1);   // round-to-nearest-even
    return (unsigned short)(r >> 16);
}
// packed f32x2 -> bf16x2 (native v_cvt_pk_bf16_f32, RNE — matches f2bf)
__device__ __forceinline__ unsigned cvtpk(float a, float b) {
    __hip_bfloat162 h = __float22bfloat162_rn(float2{a, b});
    return *reinterpret_cast<unsigned*>(&h);
}
__device__ __forceinline__ float bflo(unsigned int u) { return __uint_as_float(u << 16); }
__device__ __forceinline__ float bfhi(unsigned int u) { return __uint_as_float(u & 0xFFFF0000u); }
__device__ __forceinline__ float bf2f(short s) {
    return __uint_as_float(((unsigned int)(unsigned short)s) << 16);
}

// async global->LDS, 16B per lane, dest = wave-uniform base + lane*16 (HW rule)
__device__ __forceinline__ void gload16(const float* g, float* l) {
    __builtin_amdgcn_global_load_lds(
        (const __attribute__((address_space(1))) void*)g,
        (__attribute__((address_space(3))) void*)l, 16, 0, 0);
}

__device__ __forceinline__ int src_range(int s) {
    return (s >= R2) ? 2 : (s >= R1 ? 1 : 0);
}

// ---------------- CSR build (rows padded to multiple of 4, dummy = N_NODES;
// sources within each row grouped by source range) ----------------
__global__ void hist_kernel(const int* __restrict__ src, const int* __restrict__ dst,
                            int* __restrict__ deg, int* __restrict__ deg_r) {
    int e = blockIdx.x * blockDim.x + threadIdx.x;
    if (e < N_EDGES) {
        int d = dst[e];
        atomicAdd(&deg[d], 1);
        int r = src_range(src[e]);
        atomicAdd(&deg_r[r * N_NODES + d], 1);
    }
}

__global__ void scan1_kernel(const int* __restrict__ deg, int* __restrict__ row_start,
                             int* __restrict__ blk_sum) {
    __shared__ int sd[1024];
    int t = threadIdx.x;
    int i = blockIdx.x * 1024 + t;
    int v = (i < N_NODES) ? ((deg[i] + 3) & ~3) : 0;   // padded degree
    sd[t] = v;
    __syncthreads();
    for (int off = 1; off < 1024; off <<= 1) {
        int tv = (t >= off) ? sd[t - off] : 0;
        __syncthreads();
        sd[t] += tv;
        __syncthreads();
    }
    if (i < N_NODES) row_start[i] = sd[t] - v;          // exclusive, block-local
    if (t == 1023) blk_sum[blockIdx.x] = sd[1023];
}

// scan2 fused (wave-reduce of prior block sums) + pad fused (dummy tail) +
// per-range sub-offsets (rsub) for range-grouped fill
__global__ void scan3_kernel(int* __restrict__ row_start, const int* __restrict__ blk_sum,
                             const int* __restrict__ deg, const int* __restrict__ deg_r,
                             int* __restrict__ rsub, int* __restrict__ csr_src) {
    __shared__ int soff;
    int t = threadIdx.x;
    if (t < 64) {
        int v = (t < blockIdx.x) ? blk_sum[t] : 0;      // bid <= 48 < 64 lanes
#pragma unroll
        for (int off = 1; off < 64; off <<= 1) v += __shfl_xor(v, off);
        if (t == 0) soff = v;
    }
    __syncthreads();
    int i = blockIdx.x * 1024 + t;
    if (i < N_NODES) {
        int rs = row_start[i] + soff;
        row_start[i] = rs;
        int d = deg[i], pd = (d + 3) & ~3;
        for (int p = d; p < pd; p++) csr_src[rs + p] = N_NODES;  // dummy zero row
        int dr0 = deg_r[i], dr1 = deg_r[N_NODES + i];
        rsub[i]               = rs;               // range-0 start
        rsub[N_NODES + i]     = rs + dr0;         // range-1 start
        rsub[2 * N_NODES + i] = rs + dr0 + dr1;   // range-2 start
    }
}

__global__ void fill_kernel(const int* __restrict__ src, const int* __restrict__ dst,
                            const int* __restrict__ rsub, int* __restrict__ cursor3,
                            int* __restrict__ csr_src) {
    int e = blockIdx.x * blockDim.x + threadIdx.x;
    if (e < N_EDGES) {
        int s = src[e], d = dst[e];
        int rd = src_range(s) * N_NODES + d;
        int pos = rsub[rd] + atomicAdd(&cursor3[rd], 1);
        csr_src[pos] = s;
    }
}

// -------- degree-bucket permutation, contention-free counting sort (3 passes) --------
__global__ __launch_bounds__(256) void bin_hist2_kernel(
        const int* __restrict__ deg, int* __restrict__ node_rank,
        int* __restrict__ blk_bin_cnt) {
    __shared__ int lh[64];
    int t = threadIdx.x;
    if (t < 64) lh[t] = 0;
    __syncthreads();
    int n = blockIdx.x * 256 + t;
    if (n < N_NODES) {
        int nq = (deg[n] + 3) >> 2; if (nq > 63) nq = 63;
        node_rank[n] = atomicAdd(&lh[nq], 1);      // LDS atomic: block-private
    }
    __syncthreads();
    if (t < 64) blk_bin_cnt[blockIdx.x * 64 + t] = lh[t];
}

__global__ void bin_offsets_kernel(const int* __restrict__ blk_bin_cnt,
                                   int* __restrict__ blk_bin_off,
                                   int* __restrict__ bin_base) {
    __shared__ int tot[64];
    int b = threadIdx.x;  // 0..63
    int acc = 0;
    for (int blk = 0; blk < NBB; blk++) {
        blk_bin_off[blk * 64 + b] = acc;
        acc += blk_bin_cnt[blk * 64 + b];
    }
    tot[b] = acc;
    __syncthreads();
    if (b == 0) {
        int a = 0;
        for (int i = 63; i >= 0; i--) { bin_base[i] = a; a += tot[i]; }
    }
}

__global__ __launch_bounds__(256) void bin_place_kernel(
        const int* __restrict__ deg, const int* __restrict__ node_rank,
        const int* __restrict__ blk_bin_off, const int* __restrict__ bin_base,
        int* __restrict__ perm) {
    int n = blockIdx.x * 256 + threadIdx.x;
    if (n < N_NODES) {
        int nq = (deg[n] + 3) >> 2; if (nq > 63) nq = 63;
        perm[bin_base[nq] + blk_bin_off[blockIdx.x * 64 + nq] + node_rank[n]] = n;
    }
}

// ---------------- weight converts ----------------
// W_in fp32 [512][96] -> fragment-tiled bf16: WtT[((ks*6+n)*64 + lane)*8 + j]
__global__ void convert_win_kernel(const float* __restrict__ W, short* __restrict__ Wt) {
    int t = blockIdx.x * 256 + threadIdx.x;          // 0..6143
    int lane = t & 63;
    int n    = (t >> 6) % 6;
    int ks   = t / 384;
    int quad = lane >> 4, l16 = lane & 15;
    short8 v;
#pragma unroll
    for (int j = 0; j < 8; j++)
        v[j] = (short)f2bf(W[(size_t)(ks * 32 + quad * 8 + j) * HID + n * 16 + l16]);
    *(short8*)&Wt[(size_t)t * 8] = v;
}

// + fused dummy-row zeroing (block 0; HID==blockDim)
__global__ void convert_wout_kernel(const float* __restrict__ W, short* __restrict__ Wt,
                                    short* __restrict__ h0, short* __restrict__ hb,
                                    short* __restrict__ hc) {
    int n = blockIdx.x;    // 0..63
    int k = threadIdx.x;   // 0..95
    Wt[(size_t)n * HID + k] = (short)f2bf(W[(size_t)k * NCLASS + n]);
    if (n == 0) {
        h0[(size_t)N_NODES * HID + k] = 0;
        hb[(size_t)N_NODES * HID + k] = 0;
        hc[(size_t)N_NODES * HID + k] = 0;
    }
}

// conv_W[l][k][n] fp32 -> Wc[l][n][k] bf16 (col-major per layer)
__global__ void convert_wconv_kernel(const float* __restrict__ W, short* __restrict__ Wc) {
    int n = blockIdx.x;    // 0..95
    int l = blockIdx.y;    // 0..7
    int k = threadIdx.x;   // 0..95
    Wc[(size_t)l * HID * HID + (size_t)n * HID + k] =
        (short)f2bf(W[(size_t)l * HID * HID + (size_t)k * HID + n]);
}

// ---------------- input GEMM via MFMA bf16 (unchanged from R7) ----------
__global__ __launch_bounds__(256) void gemm_in_kernel(
        const float* __restrict__ x, const short* __restrict__ WtT,
        const float* __restrict__ b, short* __restrict__ h0) {
    __shared__ __align__(16) float As[2][4096];   // 2 x 16KB; per-wave-private 1024 floats
    int tid  = threadIdx.x;
    int wave = tid >> 6, lane = tid & 63;
    int quad = lane >> 4, l16 = lane & 15;
    int row0 = blockIdx.x * 64;

    const float* gsrc[4];
#pragma unroll
    for (int r = 0; r < 4; r++) {
        int rl  = r * 4 + (lane >> 4);           // local row in wave tile, 0..15
        int row = row0 + wave * 16 + rl;
        if (row >= N_NODES) row = N_NODES - 1;   // clamp: dup row, stores masked
        int c2s = (lane & 15) ^ rl;              // swizzled 16B-chunk index
        gsrc[r] = &x[(size_t)row * NFEAT + c2s * 4];
    }

    f32x4 acc[6];
#pragma unroll
    for (int n = 0; n < 6; n++) acc[n] = (f32x4){0.f, 0.f, 0.f, 0.f};

    float* lb0 = &As[0][wave * 1024];
    float* lb1 = &As[1][wave * 1024];
#pragma unroll
    for (int r = 0; r < 4; r++) gload16(gsrc[r], lb0 + r * 256);

#pragma unroll
    for (int c = 0; c < 8; c++) {
        if (c < 7) {
            float* nb = ((c + 1) & 1) ? lb1 : lb0;
#pragma unroll
            for (int r = 0; r < 4; r++) gload16(gsrc[r] + (c + 1) * 64, nb + r * 256);
            asm volatile("s_waitcnt vmcnt(4)" ::: "memory");
        } else {
            asm volatile("s_waitcnt vmcnt(0)" ::: "memory");
        }
        __builtin_amdgcn_sched_barrier(0);
        const float* cb = ((c & 1) ? lb1 : lb0) + l16 * 64;
#pragma unroll
        for (int s = 0; s < 2; s++) {
            int c2a = s * 8 + quad * 2;
            f32x4 fa = *(const f32x4*)&cb[((c2a    ) ^ l16) * 4];
            f32x4 fb = *(const f32x4*)&cb[((c2a + 1) ^ l16) * 4];
            union { short8 sv; uint4 u; } af;
            af.u.x = cvtpk(fa[0], fa[1]);
            af.u.y = cvtpk(fa[2], fa[3]);
            af.u.z = cvtpk(fb[0], fb[1]);
            af.u.w = cvtpk(fb[2], fb[3]);
            int ks = c * 2 + s;
            const short* bbase = &WtT[(size_t)(ks * 6) * 512 + lane * 8];
#pragma unroll
            for (int n = 0; n < 6; n++) {
                short8 bfrag = *(const short8*)&bbase[n * 512];
                acc[n] = __builtin_amdgcn_mfma_f32_16x16x32_bf16(af.sv, bfrag, acc[n], 0, 0, 0);
            }
        }
    }

    int row0w = row0 + wave * 16;
#pragma unroll
    for (int n = 0; n < 6; n++) {
        int col = n * 16 + l16;
        float bias = b[col];
#pragma unroll
        for (int r = 0; r < 4; r++) {
            int grow = row0w + quad * 4 + r;
            if (grow < N_NODES) {
                float v = acc[n][r] + bias;
                v = v > 0.f ? v : 0.f;
                h0[(size_t)grow * HID + col] = (short)f2bf(v);
            }
        }
    }
}

// ---------------- fused layer (R7 structure, UNCHANGED — the locality win comes
// from the range-grouped CSR order: all blocks gather range-0 rows (~3.2MB) first,
// then range-1, range-2; each phase's working set fits the 4MB per-XCD L2). ----
__global__ __launch_bounds__(384) void layer_kernel(
        const short* __restrict__ h_in, const short* __restrict__ x0bf,
        const int* __restrict__ row_start, const int* __restrict__ deg,
        const int* __restrict__ csr_src, const int* __restrict__ perm,
        const short* __restrict__ Wc, float beta, short* __restrict__ h_out) {
    __shared__ short As[32][104];   // hc bf16, row stride 104 shorts (208 B)
    __shared__ int   snode[32];
    int tid = threadIdx.x;
    int tx = tid % 12;              // feature chunk
    int ty = tid / 12;              // node slot 0..31
    int idx = blockIdx.x * 32 + ty;
    bool valid = idx < N_NODES;
    int node = valid ? perm[idx] : (N_NODES - 1);
    if (tx == 0) snode[ty] = valid ? node : -1;

    int s = row_start[node];
    int d = deg[node];
    int nq = (d + 3) >> 2;
    const int4* c4 = (const int4*)(csr_src + s);
    // hoist x0 row (independent of gather chain)
    uint4 xq = *(const uint4*)&x0bf[(size_t)node * HID + tx * 8];

    float acc[8];
#pragma unroll
    for (int j = 0; j < 8; j++) acc[j] = 0.f;
    int4 nv = {N_NODES, N_NODES, N_NODES, N_NODES};
    if (nq > 0) nv = c4[0];
    for (int i = 0; i < nq; i++) {
        int4 iv = nv;
        if (i + 1 < nq) nv = c4[i + 1];    // index-ahead: off the serial chain
        uint4 a0 = *(const uint4*)&h_in[(size_t)iv.x * HID + tx * 8];
        uint4 a1 = *(const uint4*)&h_in[(size_t)iv.y * HID + tx * 8];
        uint4 a2 = *(const uint4*)&h_in[(size_t)iv.z * HID + tx * 8];
        uint4 a3 = *(const uint4*)&h_in[(size_t)iv.w * HID + tx * 8];
        acc[0] += bflo(a0.x) + bflo(a1.x) + bflo(a2.x) + bflo(a3.x);
        acc[1] += bfhi(a0.x) + bfhi(a1.x) + bfhi(a2.x) + bfhi(a3.x);
        acc[2] += bflo(a0.y) + bflo(a1.y) + bflo(a2.y) + bflo(a3.y);
        acc[3] += bfhi(a0.y) + bfhi(a1.y) + bfhi(a2.y) + bfhi(a3.y);
        acc[4] += bflo(a0.z) + bflo(a1.z) + bflo(a2.z) + bflo(a3.z);
        acc[5] += bfhi(a0.z) + bfhi(a1.z) + bfhi(a2.z) + bfhi(a3.z);
        acc[6] += bflo(a0.w) + bflo(a1.w) + bflo(a2.w) + bflo(a3.w);
        acc[7] += bfhi(a0.w) + bfhi(a1.w) + bfhi(a2.w) + bfhi(a3.w);
    }
    float hc[8];
    hc[0] = (1.f - ALPHA) * acc[0] + ALPHA * bflo(xq.x);
    hc[1] = (1.f - ALPHA) * acc[1] + ALPHA * bfhi(xq.x);
    hc[2] = (1.f - ALPHA) * acc[2] + ALPHA * bflo(xq.y);
    hc[3] = (1.f - ALPHA) * acc[3] + ALPHA * bfhi(xq.y);
    hc[4] = (1.f - ALPHA) * acc[4] + ALPHA * bflo(xq.z);
    hc[5] = (1.f - ALPHA) * acc[5] + ALPHA * bfhi(xq.z);
    hc[6] = (1.f - ALPHA) * acc[6] + ALPHA * bflo(xq.w);
    hc[7] = (1.f - ALPHA) * acc[7] + ALPHA * bfhi(xq.w);
    {
        uint4 pk;
        pk.x = cvtpk(hc[0], hc[1]);
        pk.y = cvtpk(hc[2], hc[3]);
        pk.z = cvtpk(hc[4], hc[5]);
        pk.w = cvtpk(hc[6], hc[7]);
        *(uint4*)&As[ty][tx * 8] = pk;
    }
    __syncthreads();

    // Phase 2: MFMA conv. wave -> row-tile rt (0..1), col-tile pair (0..2).
    int wave = tid >> 6, lane = tid & 63;
    int quad = lane >> 4, l16 = lane & 15;
    int rt = wave & 1;
    int ct0 = (wave >> 1) * 2, ct1 = ct0 + 1;

    f32x4 g0 = (f32x4){0.f,0.f,0.f,0.f}, g1 = (f32x4){0.f,0.f,0.f,0.f};
#pragma unroll
    for (int ks = 0; ks < 3; ks++) {
        short8 afrag = *(const short8*)&As[rt * 16 + l16][ks * 32 + quad * 8];
        short8 b0 = *(const short8*)&Wc[(size_t)(ct0 * 16 + l16) * HID + ks * 32 + quad * 8];
        short8 b1 = *(const short8*)&Wc[(size_t)(ct1 * 16 + l16) * HID + ks * 32 + quad * 8];
        g0 = __builtin_amdgcn_mfma_f32_16x16x32_bf16(afrag, b0, g0, 0, 0, 0);
        g1 = __builtin_amdgcn_mfma_f32_16x16x32_bf16(afrag, b1, g1, 0, 0, 0);
    }
    float ob = 1.0f - beta;
#pragma unroll
    for (int r = 0; r < 4; r++) {
        int lrow = rt * 16 + quad * 4 + r;
        int nd = snode[lrow];
        if (nd >= 0) {
            int c0 = ct0 * 16 + l16;
            int c1 = ct1 * 16 + l16;
            float v0 = ob * bf2f(As[lrow][c0]) + beta * g0[r];
            float v1 = ob * bf2f(As[lrow][c1]) + beta * g1[r];
            v0 = v0 > 0.f ? v0 : 0.f;
            v1 = v1 > 0.f ? v1 : 0.f;
            h_out[(size_t)nd * HID + c0] = (short)f2bf(v0);
            h_out[(size_t)nd * HID + c1] = (short)f2bf(v1);
        }
    }
}

// ---------------- output GEMM (MFMA bf16) + fused log_softmax ----------------
__global__ __launch_bounds__(256) void out_kernel(
        const short* __restrict__ h_bf, const short* __restrict__ Wt,
        const float* __restrict__ b, float* __restrict__ out) {
    int tid = threadIdx.x;
    int wave = tid >> 6, lane = tid & 63;
    int quad = lane >> 4, l16 = lane & 15;
    int row0 = blockIdx.x * 64 + wave * 16;

    f32x4 acc[4];
#pragma unroll
    for (int n = 0; n < 4; n++) acc[n] = (f32x4){0.f, 0.f, 0.f, 0.f};

    int arow = row0 + l16; if (arow > N_NODES) arow = N_NODES;  // dummy row is zero
#pragma unroll
    for (int ks = 0; ks < 3; ks++) {
        short8 afrag = *(const short8*)&h_bf[(size_t)arow * HID + ks * 32 + quad * 8];
#pragma unroll
        for (int n = 0; n < 4; n++) {
            short8 bfrag = *(const short8*)&Wt[(size_t)(n * 16 + l16) * HID + ks * 32 + quad * 8];
            acc[n] = __builtin_amdgcn_mfma_f32_16x16x32_bf16(afrag, bfrag, acc[n], 0, 0, 0);
        }
    }
#pragma unroll
    for (int n = 0; n < 4; n++) {
        float bias = b[n * 16 + l16];
#pragma unroll
        for (int r = 0; r < 4; r++) acc[n][r] += bias;
    }
#pragma unroll
    for (int r = 0; r < 4; r++) {
        float m = acc[0][r];
        m = fmaxf(m, acc[1][r]); m = fmaxf(m, acc[2][r]); m = fmaxf(m, acc[3][r]);
#pragma unroll
        for (int off = 1; off < 16; off <<= 1) m = fmaxf(m, __shfl_xor(m, off));
        float s = __expf(acc[0][r] - m) + __expf(acc[1][r] - m)
                + __expf(acc[2][r] - m) + __expf(acc[3][r] - m);
#pragma unroll
        for (int off = 1; off < 16; off <<= 1) s += __shfl_xor(s, off);
        float lse = m + __logf(s);
        int grow = row0 + quad * 4 + r;
        if (grow < N_NODES) {
#pragma unroll
            for (int n = 0; n < 4; n++)
                out[(size_t)grow * NCLASS + n * 16 + l16] = acc[n][r] - lse;
        }
    }
}

extern "C" void kernel_launch(void* const* d_in, const int* in_sizes, int n_in,
                              void* d_out, int out_size, void* d_ws, size_t ws_size,
                              hipStream_t stream) {
    const float* x      = (const float*)d_in[0];
    const int*   ei     = (const int*)d_in[1];
    const int*   srcp   = ei;
    const int*   dstp   = ei + N_EDGES;
    const float* W_in   = (const float*)d_in[2];
    const float* b_in   = (const float*)d_in[3];
    const float* conv_W = (const float*)d_in[4];
    const float* W_out  = (const float*)d_in[5];
    const float* b_out  = (const float*)d_in[6];
    float* out = (float*)d_out;

    short* h0  = (short*)d_ws;                               // (N+1) x HID bf16 == x0
    short* h_b = h0  + (size_t)(N_NODES + 1) * HID;
    short* h_c = h_b + (size_t)(N_NODES + 1) * HID;
    short* Wt_in  = h_c + (size_t)(N_NODES + 1) * HID;       // 96 x 512 (fragment-tiled)
    short* Wt_out = Wt_in + (size_t)HID * NFEAT;             // 64 x 96
    short* Wc     = Wt_out + (size_t)NCLASS * HID;           // 8 x 96 x 96 bf16
    // zero-init cluster (one memset): deg (N) + deg_r (3N) + cursor3 (3N) = 7N ints
    int* deg        = (int*)(Wc + (size_t)NUM_LAYERS * HID * HID);
    int* deg_r      = deg + N_NODES;                         // 3N
    int* cursor3    = deg_r + 3 * N_NODES;                   // 3N
    int* row_start  = cursor3 + 3 * N_NODES;
    int* rsub       = row_start + N_NODES;                   // 3N
    int* blk_sum    = rsub + 3 * N_NODES;
    int* bin_base   = blk_sum + 64;
    int* node_rank  = bin_base + 64;
    int* perm       = node_rank + N_NODES;
    int* blk_bin_cnt= perm + N_NODES;                        // NBB*64
    int* blk_bin_off= blk_bin_cnt + NBB * 64;                // NBB*64
    int* csr_src    = blk_bin_off + NBB * 64;                // <= N_EDGES + 3*N_NODES ints

    hipMemsetAsync(deg, 0, 7 * N_NODES * sizeof(int), stream);   // deg + deg_r + cursor3
    hist_kernel<<<(N_EDGES + 255) / 256, 256, 0, stream>>>(srcp, dstp, deg, deg_r);
    scan1_kernel<<<NSB, 1024, 0, stream>>>(deg, row_start, blk_sum);
    scan3_kernel<<<NSB, 1024, 0, stream>>>(row_start, blk_sum, deg, deg_r, rsub, csr_src);
    fill_kernel<<<(N_EDGES + 255) / 256, 256, 0, stream>>>(srcp, dstp, rsub, cursor3, csr_src);
    bin_hist2_kernel<<<NBB, 256, 0, stream>>>(deg, node_rank, blk_bin_cnt);
    bin_offsets_kernel<<<1, 64, 0, stream>>>(blk_bin_cnt, blk_bin_off, bin_base);
    bin_place_kernel<<<NBB, 256, 0, stream>>>(deg, node_rank, blk_bin_off, bin_base, perm);

    convert_win_kernel<<<24, 256, 0, stream>>>(W_in, Wt_in);
    convert_wout_kernel<<<NCLASS, HID, 0, stream>>>(W_out, Wt_out, h0, h_b, h_c);
    convert_wconv_kernel<<<dim3(HID, NUM_LAYERS), HID, 0, stream>>>(conv_W, Wc);
    gemm_in_kernel<<<(N_NODES + 63) / 64, 256, 0, stream>>>(x, Wt_in, b_in, h0);

    short* cur = h0;
    short* nxt = h_b;
    for (int l = 0; l < NUM_LAYERS; l++) {
        float beta = logf(0.5f / (float)(l + 1) + 1.0f);
        layer_kernel<<<(N_NODES + 31) / 32, 384, 0, stream>>>(
            cur, h0, row_start, deg, csr_src, perm, Wc + (size_t)l * HID * HID, beta, nxt);
        cur = nxt;
        nxt = (cur == h_b) ? h_c : h_b;
    }

    out_kernel<<<(N_NODES + 63) / 64, 256, 0, stream>>>(cur, Wt_out, b_out, out);
}

// Round 10
// 508.617 us; speedup vs baseline: 1.0409x; 1.0409x over previous
//
#include <hip/hip_runtime.h>
#include <hip/hip_bf16.h>
#include <math.h>

#define N_NODES 50000
#define N_EDGES 800000
#define NFEAT   512
#define HID     96
#define NCLASS  64
#define NUM_LAYERS 8
#define ALPHA   0.1f
#define NSB     49          // scan blocks: ceil(50000/1024)
#define NBB     196         // bin blocks: ceil(50000/256)
// source-range split for L2 phase locality: 3 ranges x ~16.7k rows (~3.2MB of h each,
// fits the 4MB per-XCD L2). CSR rows store sources grouped by range. Range counts are
// bit-packed (3 x 10-bit fields; max per-range in-degree ~25 << 1023, no carry).
#define R1      16667
#define R2      33334

typedef __attribute__((ext_vector_type(8))) short short8;
typedef __attribute__((ext_vector_type(4))) float f32x4;

__device__ __forceinline__ unsigned short f2bf(float f) {
    unsigned int u = __float_as_uint(f);
    unsigned int r = u + 0x7FFF + ((u >> 16) & 1);   // round-to-nearest-even
    return (unsigned short)(r >> 16);
}
// packed f32x2 -> bf16x2 (native v_cvt_pk_bf16_f32, RNE — matches f2bf)
__device__ __forceinline__ unsigned cvtpk(float a, float b) {
    __hip_bfloat162 h = __float22bfloat162_rn(float2{a, b});
    return *reinterpret_cast<unsigned*>(&h);
}
__device__ __forceinline__ float bflo(unsigned int u) { return __uint_as_float(u << 16); }
__device__ __forceinline__ float bfhi(unsigned int u) { return __uint_as_float(u & 0xFFFF0000u); }
__device__ __forceinline__ float bf2f(short s) {
    return __uint_as_float(((unsigned int)(unsigned short)s) << 16);
}

// async global->LDS, 16B per lane, dest = wave-uniform base + lane*16 (HW rule)
__device__ __forceinline__ void gload16(const float* g, float* l) {
    __builtin_amdgcn_global_load_lds(
        (const __attribute__((address_space(1))) void*)g,
        (__attribute__((address_space(3))) void*)l, 16, 0, 0);
}

__device__ __forceinline__ int src_range(int s) {
    return (s >= R2) ? 2 : (s >= R1 ? 1 : 0);
}

// ---------------- CSR build (rows padded to multiple of 4, dummy = N_NODES;
// sources within each row grouped by source range; packed range histogram) ------
__global__ void hist_kernel(const int* __restrict__ src, const int* __restrict__ dst,
                            unsigned* __restrict__ degpack) {
    int e = blockIdx.x * blockDim.x + threadIdx.x;
    if (e < N_EDGES) {
        int r = src_range(src[e]);
        atomicAdd(&degpack[dst[e]], 1u << (10 * r));   // single atomic per edge
    }
}

__global__ void scan1_kernel(const unsigned* __restrict__ degpack,
                             int* __restrict__ deg, int* __restrict__ row_start,
                             int* __restrict__ blk_sum) {
    __shared__ int sd[1024];
    int t = threadIdx.x;
    int i = blockIdx.x * 1024 + t;
    unsigned p = (i < N_NODES) ? degpack[i] : 0u;
    int dt = (int)((p & 1023u) + ((p >> 10) & 1023u) + ((p >> 20) & 1023u));
    int v = (i < N_NODES) ? ((dt + 3) & ~3) : 0;       // padded degree
    sd[t] = v;
    __syncthreads();
    for (int off = 1; off < 1024; off <<= 1) {
        int tv = (t >= off) ? sd[t - off] : 0;
        __syncthreads();
        sd[t] += tv;
        __syncthreads();
    }
    if (i < N_NODES) {
        row_start[i] = sd[t] - v;                      // exclusive, block-local
        deg[i] = dt;                                   // materialize total degree
    }
    if (t == 1023) blk_sum[blockIdx.x] = sd[1023];
}

// scan2 fused (wave-reduce of prior block sums) + pad fused (dummy tail) +
// per-range sub-offsets (rsub) for range-grouped fill
__global__ void scan3_kernel(int* __restrict__ row_start, const int* __restrict__ blk_sum,
                             const int* __restrict__ deg, const unsigned* __restrict__ degpack,
                             int* __restrict__ rsub, int* __restrict__ csr_src) {
    __shared__ int soff;
    int t = threadIdx.x;
    if (t < 64) {
        int v = (t < blockIdx.x) ? blk_sum[t] : 0;      // bid <= 48 < 64 lanes
#pragma unroll
        for (int off = 1; off < 64; off <<= 1) v += __shfl_xor(v, off);
        if (t == 0) soff = v;
    }
    __syncthreads();
    int i = blockIdx.x * 1024 + t;
    if (i < N_NODES) {
        int rs = row_start[i] + soff;
        row_start[i] = rs;
        int d = deg[i], pd = (d + 3) & ~3;
        for (int p = d; p < pd; p++) csr_src[rs + p] = N_NODES;  // dummy zero row
        unsigned pk = degpack[i];
        int dr0 = (int)(pk & 1023u), dr1 = (int)((pk >> 10) & 1023u);
        rsub[i]               = rs;               // range-0 start
        rsub[N_NODES + i]     = rs + dr0;         // range-1 start
        rsub[2 * N_NODES + i] = rs + dr0 + dr1;   // range-2 start
    }
}

__global__ void fill_kernel(const int* __restrict__ src, const int* __restrict__ dst,
                            const int* __restrict__ rsub, unsigned* __restrict__ cursorpack,
                            int* __restrict__ csr_src) {
    int e = blockIdx.x * blockDim.x + threadIdx.x;
    if (e < N_EDGES) {
        int s = src[e], d = dst[e];
        int r = src_range(s);
        unsigned old = atomicAdd(&cursorpack[d], 1u << (10 * r));  // single atomic
        int cnt = (int)((old >> (10 * r)) & 1023u);
        csr_src[rsub[r * N_NODES + d] + cnt] = s;
    }
}

// -------- degree-bucket permutation, contention-free counting sort (3 passes) --------
__global__ __launch_bounds__(256) void bin_hist2_kernel(
        const int* __restrict__ deg, int* __restrict__ node_rank,
        int* __restrict__ blk_bin_cnt) {
    __shared__ int lh[64];
    int t = threadIdx.x;
    if (t < 64) lh[t] = 0;
    __syncthreads();
    int n = blockIdx.x * 256 + t;
    if (n < N_NODES) {
        int nq = (deg[n] + 3) >> 2; if (nq > 63) nq = 63;
        node_rank[n] = atomicAdd(&lh[nq], 1);      // LDS atomic: block-private
    }
    __syncthreads();
    if (t < 64) blk_bin_cnt[blockIdx.x * 64 + t] = lh[t];
}

__global__ void bin_offsets_kernel(const int* __restrict__ blk_bin_cnt,
                                   int* __restrict__ blk_bin_off,
                                   int* __restrict__ bin_base) {
    __shared__ int tot[64];
    int b = threadIdx.x;  // 0..63
    int acc = 0;
    for (int blk = 0; blk < NBB; blk++) {
        blk_bin_off[blk * 64 + b] = acc;
        acc += blk_bin_cnt[blk * 64 + b];
    }
    tot[b] = acc;
    __syncthreads();
    if (b == 0) {
        int a = 0;
        for (int i = 63; i >= 0; i--) { bin_base[i] = a; a += tot[i]; }
    }
}

__global__ __launch_bounds__(256) void bin_place_kernel(
        const int* __restrict__ deg, const int* __restrict__ node_rank,
        const int* __restrict__ blk_bin_off, const int* __restrict__ bin_base,
        int* __restrict__ perm) {
    int n = blockIdx.x * 256 + threadIdx.x;
    if (n < N_NODES) {
        int nq = (deg[n] + 3) >> 2; if (nq > 63) nq = 63;
        perm[bin_base[nq] + blk_bin_off[blockIdx.x * 64 + nq] + node_rank[n]] = n;
    }
}

// ---------------- weight converts ----------------
// W_in fp32 [512][96] -> fragment-tiled bf16: WtT[((ks*6+n)*64 + lane)*8 + j]
__global__ void convert_win_kernel(const float* __restrict__ W, short* __restrict__ Wt) {
    int t = blockIdx.x * 256 + threadIdx.x;          // 0..6143
    int lane = t & 63;
    int n    = (t >> 6) % 6;
    int ks   = t / 384;
    int quad = lane >> 4, l16 = lane & 15;
    short8 v;
#pragma unroll
    for (int j = 0; j < 8; j++)
        v[j] = (short)f2bf(W[(size_t)(ks * 32 + quad * 8 + j) * HID + n * 16 + l16]);
    *(short8*)&Wt[(size_t)t * 8] = v;
}

// + fused dummy-row zeroing (block 0; HID==blockDim)
__global__ void convert_wout_kernel(const float* __restrict__ W, short* __restrict__ Wt,
                                    short* __restrict__ h0, short* __restrict__ hb,
                                    short* __restrict__ hc) {
    int n = blockIdx.x;    // 0..63
    int k = threadIdx.x;   // 0..95
    Wt[(size_t)n * HID + k] = (short)f2bf(W[(size_t)k * NCLASS + n]);
    if (n == 0) {
        h0[(size_t)N_NODES * HID + k] = 0;
        hb[(size_t)N_NODES * HID + k] = 0;
        hc[(size_t)N_NODES * HID + k] = 0;
    }
}

// conv_W[l][k][n] fp32 -> Wc[l][n][k] bf16 (col-major per layer)
__global__ void convert_wconv_kernel(const float* __restrict__ W, short* __restrict__ Wc) {
    int n = blockIdx.x;    // 0..95
    int l = blockIdx.y;    // 0..7
    int k = threadIdx.x;   // 0..95
    Wc[(size_t)l * HID * HID + (size_t)n * HID + k] =
        (short)f2bf(W[(size_t)l * HID * HID + (size_t)k * HID + n]);
}

// ---------------- input GEMM via MFMA bf16 (unchanged) ----------
__global__ __launch_bounds__(256) void gemm_in_kernel(
        const float* __restrict__ x, const short* __restrict__ WtT,
        const float* __restrict__ b, short* __restrict__ h0) {
    __shared__ __align__(16) float As[2][4096];   // 2 x 16KB; per-wave-private 1024 floats
    int tid  = threadIdx.x;
    int wave = tid >> 6, lane = tid & 63;
    int quad = lane >> 4, l16 = lane & 15;
    int row0 = blockIdx.x * 64;

    const float* gsrc[4];
#pragma unroll
    for (int r = 0; r < 4; r++) {
        int rl  = r * 4 + (lane >> 4);           // local row in wave tile, 0..15
        int row = row0 + wave * 16 + rl;
        if (row >= N_NODES) row = N_NODES - 1;   // clamp: dup row, stores masked
        int c2s = (lane & 15) ^ rl;              // swizzled 16B-chunk index
        gsrc[r] = &x[(size_t)row * NFEAT + c2s * 4];
    }

    f32x4 acc[6];
#pragma unroll
    for (int n = 0; n < 6; n++) acc[n] = (f32x4){0.f, 0.f, 0.f, 0.f};

    float* lb0 = &As[0][wave * 1024];
    float* lb1 = &As[1][wave * 1024];
#pragma unroll
    for (int r = 0; r < 4; r++) gload16(gsrc[r], lb0 + r * 256);

#pragma unroll
    for (int c = 0; c < 8; c++) {
        if (c < 7) {
            float* nb = ((c + 1) & 1) ? lb1 : lb0;
#pragma unroll
            for (int r = 0; r < 4; r++) gload16(gsrc[r] + (c + 1) * 64, nb + r * 256);
            asm volatile("s_waitcnt vmcnt(4)" ::: "memory");
        } else {
            asm volatile("s_waitcnt vmcnt(0)" ::: "memory");
        }
        __builtin_amdgcn_sched_barrier(0);
        const float* cb = ((c & 1) ? lb1 : lb0) + l16 * 64;
#pragma unroll
        for (int s = 0; s < 2; s++) {
            int c2a = s * 8 + quad * 2;
            f32x4 fa = *(const f32x4*)&cb[((c2a    ) ^ l16) * 4];
            f32x4 fb = *(const f32x4*)&cb[((c2a + 1) ^ l16) * 4];
            union { short8 sv; uint4 u; } af;
            af.u.x = cvtpk(fa[0], fa[1]);
            af.u.y = cvtpk(fa[2], fa[3]);
            af.u.z = cvtpk(fb[0], fb[1]);
            af.u.w = cvtpk(fb[2], fb[3]);
            int ks = c * 2 + s;
            const short* bbase = &WtT[(size_t)(ks * 6) * 512 + lane * 8];
#pragma unroll
            for (int n = 0; n < 6; n++) {
                short8 bfrag = *(const short8*)&bbase[n * 512];
                acc[n] = __builtin_amdgcn_mfma_f32_16x16x32_bf16(af.sv, bfrag, acc[n], 0, 0, 0);
            }
        }
    }

    int row0w = row0 + wave * 16;
#pragma unroll
    for (int n = 0; n < 6; n++) {
        int col = n * 16 + l16;
        float bias = b[col];
#pragma unroll
        for (int r = 0; r < 4; r++) {
            int grow = row0w + quad * 4 + r;
            if (grow < N_NODES) {
                float v = acc[n][r] + bias;
                v = v > 0.f ? v : 0.f;
                h0[(size_t)grow * HID + col] = (short)f2bf(v);
            }
        }
    }
}

// ---------------- fused layer (UNCHANGED — locality from range-grouped CSR order:
// all blocks gather range-0 rows (~3.2MB) first, then range-1, range-2; each phase's
// working set fits the 4MB per-XCD L2; measured -32us/8 layers in R9). ----
__global__ __launch_bounds__(384) void layer_kernel(
        const short* __restrict__ h_in, const short* __restrict__ x0bf,
        const int* __restrict__ row_start, const int* __restrict__ deg,
        const int* __restrict__ csr_src, const int* __restrict__ perm,
        const short* __restrict__ Wc, float beta, short* __restrict__ h_out) {
    __shared__ short As[32][104];   // hc bf16, row stride 104 shorts (208 B)
    __shared__ int   snode[32];
    int tid = threadIdx.x;
    int tx = tid % 12;              // feature chunk
    int ty = tid / 12;              // node slot 0..31
    int idx = blockIdx.x * 32 + ty;
    bool valid = idx < N_NODES;
    int node = valid ? perm[idx] : (N_NODES - 1);
    if (tx == 0) snode[ty] = valid ? node : -1;

    int s = row_start[node];
    int d = deg[node];
    int nq = (d + 3) >> 2;
    const int4* c4 = (const int4*)(csr_src + s);
    // hoist x0 row (independent of gather chain)
    uint4 xq = *(const uint4*)&x0bf[(size_t)node * HID + tx * 8];

    float acc[8];
#pragma unroll
    for (int j = 0; j < 8; j++) acc[j] = 0.f;
    int4 nv = {N_NODES, N_NODES, N_NODES, N_NODES};
    if (nq > 0) nv = c4[0];
    for (int i = 0; i < nq; i++) {
        int4 iv = nv;
        if (i + 1 < nq) nv = c4[i + 1];    // index-ahead: off the serial chain
        uint4 a0 = *(const uint4*)&h_in[(size_t)iv.x * HID + tx * 8];
        uint4 a1 = *(const uint4*)&h_in[(size_t)iv.y * HID + tx * 8];
        uint4 a2 = *(const uint4*)&h_in[(size_t)iv.z * HID + tx * 8];
        uint4 a3 = *(const uint4*)&h_in[(size_t)iv.w * HID + tx * 8];
        acc[0] += bflo(a0.x) + bflo(a1.x) + bflo(a2.x) + bflo(a3.x);
        acc[1] += bfhi(a0.x) + bfhi(a1.x) + bfhi(a2.x) + bfhi(a3.x);
        acc[2] += bflo(a0.y) + bflo(a1.y) + bflo(a2.y) + bflo(a3.y);
        acc[3] += bfhi(a0.y) + bfhi(a1.y) + bfhi(a2.y) + bfhi(a3.y);
        acc[4] += bflo(a0.z) + bflo(a1.z) + bflo(a2.z) + bflo(a3.z);
        acc[5] += bfhi(a0.z) + bfhi(a1.z) + bfhi(a2.z) + bfhi(a3.z);
        acc[6] += bflo(a0.w) + bflo(a1.w) + bflo(a2.w) + bflo(a3.w);
        acc[7] += bfhi(a0.w) + bfhi(a1.w) + bfhi(a2.w) + bfhi(a3.w);
    }
    float hc[8];
    hc[0] = (1.f - ALPHA) * acc[0] + ALPHA * bflo(xq.x);
    hc[1] = (1.f - ALPHA) * acc[1] + ALPHA * bfhi(xq.x);
    hc[2] = (1.f - ALPHA) * acc[2] + ALPHA * bflo(xq.y);
    hc[3] = (1.f - ALPHA) * acc[3] + ALPHA * bfhi(xq.y);
    hc[4] = (1.f - ALPHA) * acc[4] + ALPHA * bflo(xq.z);
    hc[5] = (1.f - ALPHA) * acc[5] + ALPHA * bfhi(xq.z);
    hc[6] = (1.f - ALPHA) * acc[6] + ALPHA * bflo(xq.w);
    hc[7] = (1.f - ALPHA) * acc[7] + ALPHA * bfhi(xq.w);
    {
        uint4 pk;
        pk.x = cvtpk(hc[0], hc[1]);
        pk.y = cvtpk(hc[2], hc[3]);
        pk.z = cvtpk(hc[4], hc[5]);
        pk.w = cvtpk(hc[6], hc[7]);
        *(uint4*)&As[ty][tx * 8] = pk;
    }
    __syncthreads();

    // Phase 2: MFMA conv. wave -> row-tile rt (0..1), col-tile pair (0..2).
    int wave = tid >> 6, lane = tid & 63;
    int quad = lane >> 4, l16 = lane & 15;
    int rt = wave & 1;
    int ct0 = (wave >> 1) * 2, ct1 = ct0 + 1;

    f32x4 g0 = (f32x4){0.f,0.f,0.f,0.f}, g1 = (f32x4){0.f,0.f,0.f,0.f};
#pragma unroll
    for (int ks = 0; ks < 3; ks++) {
        short8 afrag = *(const short8*)&As[rt * 16 + l16][ks * 32 + quad * 8];
        short8 b0 = *(const short8*)&Wc[(size_t)(ct0 * 16 + l16) * HID + ks * 32 + quad * 8];
        short8 b1 = *(const short8*)&Wc[(size_t)(ct1 * 16 + l16) * HID + ks * 32 + quad * 8];
        g0 = __builtin_amdgcn_mfma_f32_16x16x32_bf16(afrag, b0, g0, 0, 0, 0);
        g1 = __builtin_amdgcn_mfma_f32_16x16x32_bf16(afrag, b1, g1, 0, 0, 0);
    }
    float ob = 1.0f - beta;
#pragma unroll
    for (int r = 0; r < 4; r++) {
        int lrow = rt * 16 + quad * 4 + r;
        int nd = snode[lrow];
        if (nd >= 0) {
            int c0 = ct0 * 16 + l16;
            int c1 = ct1 * 16 + l16;
            float v0 = ob * bf2f(As[lrow][c0]) + beta * g0[r];
            float v1 = ob * bf2f(As[lrow][c1]) + beta * g1[r];
            v0 = v0 > 0.f ? v0 : 0.f;
            v1 = v1 > 0.f ? v1 : 0.f;
            h_out[(size_t)nd * HID + c0] = (short)f2bf(v0);
            h_out[(size_t)nd * HID + c1] = (short)f2bf(v1);
        }
    }
}

// ---------------- output GEMM (MFMA bf16) + fused log_softmax ----------------
__global__ __launch_bounds__(256) void out_kernel(
        const short* __restrict__ h_bf, const short* __restrict__ Wt,
        const float* __restrict__ b, float* __restrict__ out) {
    int tid = threadIdx.x;
    int wave = tid >> 6, lane = tid & 63;
    int quad = lane >> 4, l16 = lane & 15;
    int row0 = blockIdx.x * 64 + wave * 16;

    f32x4 acc[4];
#pragma unroll
    for (int n = 0; n < 4; n++) acc[n] = (f32x4){0.f, 0.f, 0.f, 0.f};

    int arow = row0 + l16; if (arow > N_NODES) arow = N_NODES;  // dummy row is zero
#pragma unroll
    for (int ks = 0; ks < 3; ks++) {
        short8 afrag = *(const short8*)&h_bf[(size_t)arow * HID + ks * 32 + quad * 8];
#pragma unroll
        for (int n = 0; n < 4; n++) {
            short8 bfrag = *(const short8*)&Wt[(size_t)(n * 16 + l16) * HID + ks * 32 + quad * 8];
            acc[n] = __builtin_amdgcn_mfma_f32_16x16x32_bf16(afrag, bfrag, acc[n], 0, 0, 0);
        }
    }
#pragma unroll
    for (int n = 0; n < 4; n++) {
        float bias = b[n * 16 + l16];
#pragma unroll
        for (int r = 0; r < 4; r++) acc[n][r] += bias;
    }
#pragma unroll
    for (int r = 0; r < 4; r++) {
        float m = acc[0][r];
        m = fmaxf(m, acc[1][r]); m = fmaxf(m, acc[2][r]); m = fmaxf(m, acc[3][r]);
#pragma unroll
        for (int off = 1; off < 16; off <<= 1) m = fmaxf(m, __shfl_xor(m, off));
        float s = __expf(acc[0][r] - m) + __expf(acc[1][r] - m)
                + __expf(acc[2][r] - m) + __expf(acc[3][r] - m);
#pragma unroll
        for (int off = 1; off < 16; off <<= 1) s += __shfl_xor(s, off);
        float lse = m + __logf(s);
        int grow = row0 + quad * 4 + r;
        if (grow < N_NODES) {
#pragma unroll
            for (int n = 0; n < 4; n++)
                out[(size_t)grow * NCLASS + n * 16 + l16] = acc[n][r] - lse;
        }
    }
}

extern "C" void kernel_launch(void* const* d_in, const int* in_sizes, int n_in,
                              void* d_out, int out_size, void* d_ws, size_t ws_size,
                              hipStream_t stream) {
    const float* x      = (const float*)d_in[0];
    const int*   ei     = (const int*)d_in[1];
    const int*   srcp   = ei;
    const int*   dstp   = ei + N_EDGES;
    const float* W_in   = (const float*)d_in[2];
    const float* b_in   = (const float*)d_in[3];
    const float* conv_W = (const float*)d_in[4];
    const float* W_out  = (const float*)d_in[5];
    const float* b_out  = (const float*)d_in[6];
    float* out = (float*)d_out;

    short* h0  = (short*)d_ws;                               // (N+1) x HID bf16 == x0
    short* h_b = h0  + (size_t)(N_NODES + 1) * HID;
    short* h_c = h_b + (size_t)(N_NODES + 1) * HID;
    short* Wt_in  = h_c + (size_t)(N_NODES + 1) * HID;       // 96 x 512 (fragment-tiled)
    short* Wt_out = Wt_in + (size_t)HID * NFEAT;             // 64 x 96
    short* Wc     = Wt_out + (size_t)NCLASS * HID;           // 8 x 96 x 96 bf16
    // zero-init cluster (one memset): degpack (N) + cursorpack (N) = 2N u32
    unsigned* degpack    = (unsigned*)(Wc + (size_t)NUM_LAYERS * HID * HID);
    unsigned* cursorpack = degpack + N_NODES;
    int* deg        = (int*)(cursorpack + N_NODES);
    int* row_start  = deg + N_NODES;
    int* rsub       = row_start + N_NODES;                   // 3N
    int* blk_sum    = rsub + 3 * N_NODES;
    int* bin_base   = blk_sum + 64;
    int* node_rank  = bin_base + 64;
    int* perm       = node_rank + N_NODES;
    int* blk_bin_cnt= perm + N_NODES;                        // NBB*64
    int* blk_bin_off= blk_bin_cnt + NBB * 64;                // NBB*64
    int* csr_src    = blk_bin_off + NBB * 64;                // <= N_EDGES + 3*N_NODES ints

    hipMemsetAsync(degpack, 0, 2 * N_NODES * sizeof(unsigned), stream);
    hist_kernel<<<(N_EDGES + 255) / 256, 256, 0, stream>>>(srcp, dstp, degpack);
    scan1_kernel<<<NSB, 1024, 0, stream>>>(degpack, deg, row_start, blk_sum);
    scan3_kernel<<<NSB, 1024, 0, stream>>>(row_start, blk_sum, deg, degpack, rsub, csr_src);
    fill_kernel<<<(N_EDGES + 255) / 256, 256, 0, stream>>>(srcp, dstp, rsub, cursorpack, csr_src);
    bin_hist2_kernel<<<NBB, 256, 0, stream>>>(deg, node_rank, blk_bin_cnt);
    bin_offsets_kernel<<<1, 64, 0, stream>>>(blk_bin_cnt, blk_bin_off, bin_base);
    bin_place_kernel<<<NBB, 256, 0, stream>>>(deg, node_rank, blk_bin_off, bin_base, perm);

    convert_win_kernel<<<24, 256, 0, stream>>>(W_in, Wt_in);
    convert_wout_kernel<<<NCLASS, HID, 0, stream>>>(W_out, Wt_out, h0, h_b, h_c);
    convert_wconv_kernel<<<dim3(HID, NUM_LAYERS), HID, 0, stream>>>(conv_W, Wc);
    gemm_in_kernel<<<(N_NODES + 63) / 64, 256, 0, stream>>>(x, Wt_in, b_in, h0);

    short* cur = h0;
    short* nxt = h_b;
    for (int l = 0; l < NUM_LAYERS; l++) {
        float beta = logf(0.5f / (float)(l + 1) + 1.0f);
        layer_kernel<<<(N_NODES + 31) / 32, 384, 0, stream>>>(
            cur, h0, row_start, deg, csr_src, perm, Wc + (size_t)l * HID * HID, beta, nxt);
        cur = nxt;
        nxt = (cur == h_b) ? h_c : h_b;
    }

    out_kernel<<<(N_NODES + 63) / 64, 256, 0, stream>>>(cur, Wt_out, b_out, out);
}

// Round 11
// 496.884 us; speedup vs baseline: 1.0655x; 1.0236x over previous
//
#include <hip/hip_runtime.h>
#include <hip/hip_bf16.h>
#include <math.h>

#define N_NODES 50000
#define N_EDGES 800000
#define NFEAT   512
#define HID     96
#define NCLASS  64
#define NUM_LAYERS 8
#define ALPHA   0.1f
#define NSB     49          // scan blocks: ceil(50000/1024)
#define NBB     196         // bin blocks: ceil(50000/256)
// source-range split for L2 phase locality: 3 ranges x ~16.7k rows (~3.2MB of h each,
// fits the 4MB per-XCD L2). CSR rows store sources grouped by range. Range counts are
// bit-packed (3 x 10-bit fields; max per-range in-degree ~25 << 1023, no carry).
#define R1      16667
#define R2      33334
// two-phase CSR fill: 49 dst-buckets (dst>>10), capacity 20480 (mean 16.3K, +32 sigma)
#define NBKT    49
#define BCAP    20480

typedef __attribute__((ext_vector_type(8))) short short8;
typedef __attribute__((ext_vector_type(4))) float f32x4;

__device__ __forceinline__ unsigned short f2bf(float f) {
    unsigned int u = __float_as_uint(f);
    unsigned int r = u + 0x7FFF + ((u >> 16) & 1);   // round-to-nearest-even
    return (unsigned short)(r >> 16);
}
// packed f32x2 -> bf16x2 (native v_cvt_pk_bf16_f32, RNE — matches f2bf)
__device__ __forceinline__ unsigned cvtpk(float a, float b) {
    __hip_bfloat162 h = __float22bfloat162_rn(float2{a, b});
    return *reinterpret_cast<unsigned*>(&h);
}
__device__ __forceinline__ float bflo(unsigned int u) { return __uint_as_float(u << 16); }
__device__ __forceinline__ float bfhi(unsigned int u) { return __uint_as_float(u & 0xFFFF0000u); }
__device__ __forceinline__ float bf2f(short s) {
    return __uint_as_float(((unsigned int)(unsigned short)s) << 16);
}

// async global->LDS, 16B per lane, dest = wave-uniform base + lane*16 (HW rule)
__device__ __forceinline__ void gload16(const float* g, float* l) {
    __builtin_amdgcn_global_load_lds(
        (const __attribute__((address_space(1))) void*)g,
        (__attribute__((address_space(3))) void*)l, 16, 0, 0);
}

__device__ __forceinline__ int src_range(int s) {
    return (s >= R2) ? 2 : (s >= R1 ? 1 : 0);
}

// ---------------- CSR build (rows padded to multiple of 4, dummy = N_NODES;
// sources within each row grouped by source range; packed range histogram) ------
__global__ void hist_kernel(const int* __restrict__ src, const int* __restrict__ dst,
                            unsigned* __restrict__ degpack) {
    int e = blockIdx.x * blockDim.x + threadIdx.x;
    if (e < N_EDGES) {
        int r = src_range(src[e]);
        atomicAdd(&degpack[dst[e]], 1u << (10 * r));   // single atomic per edge
    }
}

__global__ void scan1_kernel(const unsigned* __restrict__ degpack,
                             int* __restrict__ deg, int* __restrict__ row_start,
                             int* __restrict__ blk_sum) {
    __shared__ int sd[1024];
    int t = threadIdx.x;
    int i = blockIdx.x * 1024 + t;
    unsigned p = (i < N_NODES) ? degpack[i] : 0u;
    int dt = (int)((p & 1023u) + ((p >> 10) & 1023u) + ((p >> 20) & 1023u));
    int v = (i < N_NODES) ? ((dt + 3) & ~3) : 0;       // padded degree
    sd[t] = v;
    __syncthreads();
    for (int off = 1; off < 1024; off <<= 1) {
        int tv = (t >= off) ? sd[t - off] : 0;
        __syncthreads();
        sd[t] += tv;
        __syncthreads();
    }
    if (i < N_NODES) {
        row_start[i] = sd[t] - v;                      // exclusive, block-local
        deg[i] = dt;                                   // materialize total degree
    }
    if (t == 1023) blk_sum[blockIdx.x] = sd[1023];
}

// scan2 fused (wave-reduce of prior block sums) + pad fused (dummy tail) +
// per-range sub-offsets (rsub) for range-grouped fill
__global__ void scan3_kernel(int* __restrict__ row_start, const int* __restrict__ blk_sum,
                             const int* __restrict__ deg, const unsigned* __restrict__ degpack,
                             int* __restrict__ rsub, int* __restrict__ csr_src) {
    __shared__ int soff;
    int t = threadIdx.x;
    if (t < 64) {
        int v = (t < blockIdx.x) ? blk_sum[t] : 0;      // bid <= 48 < 64 lanes
#pragma unroll
        for (int off = 1; off < 64; off <<= 1) v += __shfl_xor(v, off);
        if (t == 0) soff = v;
    }
    __syncthreads();
    int i = blockIdx.x * 1024 + t;
    if (i < N_NODES) {
        int rs = row_start[i] + soff;
        row_start[i] = rs;
        int d = deg[i], pd = (d + 3) & ~3;
        for (int p = d; p < pd; p++) csr_src[rs + p] = N_NODES;  // dummy zero row
        unsigned pk = degpack[i];
        int dr0 = (int)(pk & 1023u), dr1 = (int)((pk >> 10) & 1023u);
        rsub[i]               = rs;               // range-0 start
        rsub[N_NODES + i]     = rs + dr0;         // range-1 start
        rsub[2 * N_NODES + i] = rs + dr0 + dr1;   // range-2 start
    }
}

// phase A: coarse-partition edges into 49 dst-buckets; packed (src<<10)|dst_local.
// Writes are ~42-edge contiguous runs per (block,bucket) -> near-full 64B lines
// (replaces fill_kernel's 18x write-amplified random scatter, 57.7MB -> ~payload).
__global__ __launch_bounds__(256) void partition_kernel(
        const int* __restrict__ src, const int* __restrict__ dst,
        int* __restrict__ bkt_cnt, unsigned* __restrict__ bkt) {
    __shared__ int lh[NBKT], gb[NBKT];
    int t = threadIdx.x;
    if (t < NBKT) lh[t] = 0;
    __syncthreads();
    int e0 = blockIdx.x * 2048;
    int pv[8], bv[8];
#pragma unroll
    for (int k = 0; k < 8; k++) {
        int e = e0 + k * 256 + t;                    // coalesced
        bool ok = e < N_EDGES;
        int s = ok ? src[e] : 0;
        int d = ok ? dst[e] : 0;
        bv[k] = ok ? (d >> 10) : -1;
        pv[k] = (s << 10) | (d & 1023);
        if (ok) atomicAdd(&lh[d >> 10], 1);
    }
    __syncthreads();
    if (t < NBKT) {
        int c = lh[t];
        gb[t] = c ? atomicAdd(&bkt_cnt[t], c) : 0;
        lh[t] = 0;                                   // reuse as rank cursor
    }
    __syncthreads();
#pragma unroll
    for (int k = 0; k < 8; k++) {
        int b = bv[k];
        if (b >= 0) {
            int rank = atomicAdd(&lh[b], 1);
            bkt[(size_t)b * BCAP + gb[b] + rank] = (unsigned)pv[k];
        }
    }
}

// phase B: one block per bucket -> all final CSR writes fall in one ~80KB window,
// accumulated in ONE XCD's L2 (full-line writebacks). Cursors in LDS from rsub.
__global__ __launch_bounds__(256) void place_kernel(
        const unsigned* __restrict__ bkt, const int* __restrict__ bkt_cnt,
        const int* __restrict__ rsub, int* __restrict__ csr_src) {
    __shared__ int cur[1024 * 3];
    int b = blockIdx.x, t = threadIdx.x;
    int n0 = b << 10;
    for (int ln = t; ln < 1024; ln += 256) {
        int node = n0 + ln;
        if (node < N_NODES) {
#pragma unroll
            for (int r = 0; r < 3; r++)
                cur[ln * 3 + r] = rsub[r * N_NODES + node];
        }
    }
    __syncthreads();
    int cnt = bkt_cnt[b];
    const unsigned* bp = &bkt[(size_t)b * BCAP];
    for (int i = t; i < cnt; i += 256) {
        unsigned p = bp[i];
        int s  = (int)(p >> 10);
        int ln = (int)(p & 1023u);
        int r = src_range(s);
        int pos = atomicAdd(&cur[ln * 3 + r], 1);
        csr_src[pos] = s;
    }
}

// -------- degree-bucket permutation, contention-free counting sort (3 passes) --------
__global__ __launch_bounds__(256) void bin_hist2_kernel(
        const int* __restrict__ deg, int* __restrict__ node_rank,
        int* __restrict__ blk_bin_cnt) {
    __shared__ int lh[64];
    int t = threadIdx.x;
    if (t < 64) lh[t] = 0;
    __syncthreads();
    int n = blockIdx.x * 256 + t;
    if (n < N_NODES) {
        int nq = (deg[n] + 3) >> 2; if (nq > 63) nq = 63;
        node_rank[n] = atomicAdd(&lh[nq], 1);      // LDS atomic: block-private
    }
    __syncthreads();
    if (t < 64) blk_bin_cnt[blockIdx.x * 64 + t] = lh[t];
}

__global__ void bin_offsets_kernel(const int* __restrict__ blk_bin_cnt,
                                   int* __restrict__ blk_bin_off,
                                   int* __restrict__ bin_base) {
    __shared__ int tot[64];
    int b = threadIdx.x;  // 0..63
    int acc = 0;
    for (int blk = 0; blk < NBB; blk++) {
        blk_bin_off[blk * 64 + b] = acc;
        acc += blk_bin_cnt[blk * 64 + b];
    }
    tot[b] = acc;
    __syncthreads();
    if (b == 0) {
        int a = 0;
        for (int i = 63; i >= 0; i--) { bin_base[i] = a; a += tot[i]; }
    }
}

__global__ __launch_bounds__(256) void bin_place_kernel(
        const int* __restrict__ deg, const int* __restrict__ node_rank,
        const int* __restrict__ blk_bin_off, const int* __restrict__ bin_base,
        int* __restrict__ perm) {
    int n = blockIdx.x * 256 + threadIdx.x;
    if (n < N_NODES) {
        int nq = (deg[n] + 3) >> 2; if (nq > 63) nq = 63;
        perm[bin_base[nq] + blk_bin_off[blockIdx.x * 64 + nq] + node_rank[n]] = n;
    }
}

// ---------------- weight converts ----------------
// W_in fp32 [512][96] -> fragment-tiled bf16: WtT[((ks*6+n)*64 + lane)*8 + j]
__global__ void convert_win_kernel(const float* __restrict__ W, short* __restrict__ Wt) {
    int t = blockIdx.x * 256 + threadIdx.x;          // 0..6143
    int lane = t & 63;
    int n    = (t >> 6) % 6;
    int ks   = t / 384;
    int quad = lane >> 4, l16 = lane & 15;
    short8 v;
#pragma unroll
    for (int j = 0; j < 8; j++)
        v[j] = (short)f2bf(W[(size_t)(ks * 32 + quad * 8 + j) * HID + n * 16 + l16]);
    *(short8*)&Wt[(size_t)t * 8] = v;
}

// + fused dummy-row zeroing (block 0; HID==blockDim)
__global__ void convert_wout_kernel(const float* __restrict__ W, short* __restrict__ Wt,
                                    short* __restrict__ h0, short* __restrict__ hb,
                                    short* __restrict__ hc) {
    int n = blockIdx.x;    // 0..63
    int k = threadIdx.x;   // 0..95
    Wt[(size_t)n * HID + k] = (short)f2bf(W[(size_t)k * NCLASS + n]);
    if (n == 0) {
        h0[(size_t)N_NODES * HID + k] = 0;
        hb[(size_t)N_NODES * HID + k] = 0;
        hc[(size_t)N_NODES * HID + k] = 0;
    }
}

// conv_W[l][k][n] fp32 -> Wc[l][n][k] bf16 (col-major per layer)
__global__ void convert_wconv_kernel(const float* __restrict__ W, short* __restrict__ Wc) {
    int n = blockIdx.x;    // 0..95
    int l = blockIdx.y;    // 0..7
    int k = threadIdx.x;   // 0..95
    Wc[(size_t)l * HID * HID + (size_t)n * HID + k] =
        (short)f2bf(W[(size_t)l * HID * HID + (size_t)k * HID + n]);
}

// ---------------- input GEMM via MFMA bf16 (unchanged) ----------
__global__ __launch_bounds__(256) void gemm_in_kernel(
        const float* __restrict__ x, const short* __restrict__ WtT,
        const float* __restrict__ b, short* __restrict__ h0) {
    __shared__ __align__(16) float As[2][4096];   // 2 x 16KB; per-wave-private 1024 floats
    int tid  = threadIdx.x;
    int wave = tid >> 6, lane = tid & 63;
    int quad = lane >> 4, l16 = lane & 15;
    int row0 = blockIdx.x * 64;

    const float* gsrc[4];
#pragma unroll
    for (int r = 0; r < 4; r++) {
        int rl  = r * 4 + (lane >> 4);           // local row in wave tile, 0..15
        int row = row0 + wave * 16 + rl;
        if (row >= N_NODES) row = N_NODES - 1;   // clamp: dup row, stores masked
        int c2s = (lane & 15) ^ rl;              // swizzled 16B-chunk index
        gsrc[r] = &x[(size_t)row * NFEAT + c2s * 4];
    }

    f32x4 acc[6];
#pragma unroll
    for (int n = 0; n < 6; n++) acc[n] = (f32x4){0.f, 0.f, 0.f, 0.f};

    float* lb0 = &As[0][wave * 1024];
    float* lb1 = &As[1][wave * 1024];
#pragma unroll
    for (int r = 0; r < 4; r++) gload16(gsrc[r], lb0 + r * 256);

#pragma unroll
    for (int c = 0; c < 8; c++) {
        if (c < 7) {
            float* nb = ((c + 1) & 1) ? lb1 : lb0;
#pragma unroll
            for (int r = 0; r < 4; r++) gload16(gsrc[r] + (c + 1) * 64, nb + r * 256);
            asm volatile("s_waitcnt vmcnt(4)" ::: "memory");
        } else {
            asm volatile("s_waitcnt vmcnt(0)" ::: "memory");
        }
        __builtin_amdgcn_sched_barrier(0);
        const float* cb = ((c & 1) ? lb1 : lb0) + l16 * 64;
#pragma unroll
        for (int s = 0; s < 2; s++) {
            int c2a = s * 8 + quad * 2;
            f32x4 fa = *(const f32x4*)&cb[((c2a    ) ^ l16) * 4];
            f32x4 fb = *(const f32x4*)&cb[((c2a + 1) ^ l16) * 4];
            union { short8 sv; uint4 u; } af;
            af.u.x = cvtpk(fa[0], fa[1]);
            af.u.y = cvtpk(fa[2], fa[3]);
            af.u.z = cvtpk(fb[0], fb[1]);
            af.u.w = cvtpk(fb[2], fb[3]);
            int ks = c * 2 + s;
            const short* bbase = &WtT[(size_t)(ks * 6) * 512 + lane * 8];
#pragma unroll
            for (int n = 0; n < 6; n++) {
                short8 bfrag = *(const short8*)&bbase[n * 512];
                acc[n] = __builtin_amdgcn_mfma_f32_16x16x32_bf16(af.sv, bfrag, acc[n], 0, 0, 0);
            }
        }
    }

    int row0w = row0 + wave * 16;
#pragma unroll
    for (int n = 0; n < 6; n++) {
        int col = n * 16 + l16;
        float bias = b[col];
#pragma unroll
        for (int r = 0; r < 4; r++) {
            int grow = row0w + quad * 4 + r;
            if (grow < N_NODES) {
                float v = acc[n][r] + bias;
                v = v > 0.f ? v : 0.f;
                h0[(size_t)grow * HID + col] = (short)f2bf(v);
            }
        }
    }
}

// ---------------- fused layer (UNCHANGED — locality from range-grouped CSR order:
// all blocks gather range-0 rows (~3.2MB) first, then range-1, range-2; each phase's
// working set fits the 4MB per-XCD L2; measured -32us/8 layers in R9). ----
__global__ __launch_bounds__(384) void layer_kernel(
        const short* __restrict__ h_in, const short* __restrict__ x0bf,
        const int* __restrict__ row_start, const int* __restrict__ deg,
        const int* __restrict__ csr_src, const int* __restrict__ perm,
        const short* __restrict__ Wc, float beta, short* __restrict__ h_out) {
    __shared__ short As[32][104];   // hc bf16, row stride 104 shorts (208 B)
    __shared__ int   snode[32];
    int tid = threadIdx.x;
    int tx = tid % 12;              // feature chunk
    int ty = tid / 12;              // node slot 0..31
    int idx = blockIdx.x * 32 + ty;
    bool valid = idx < N_NODES;
    int node = valid ? perm[idx] : (N_NODES - 1);
    if (tx == 0) snode[ty] = valid ? node : -1;

    int s = row_start[node];
    int d = deg[node];
    int nq = (d + 3) >> 2;
    const int4* c4 = (const int4*)(csr_src + s);
    // hoist x0 row (independent of gather chain)
    uint4 xq = *(const uint4*)&x0bf[(size_t)node * HID + tx * 8];

    float acc[8];
#pragma unroll
    for (int j = 0; j < 8; j++) acc[j] = 0.f;
    int4 nv = {N_NODES, N_NODES, N_NODES, N_NODES};
    if (nq > 0) nv = c4[0];
    for (int i = 0; i < nq; i++) {
        int4 iv = nv;
        if (i + 1 < nq) nv = c4[i + 1];    // index-ahead: off the serial chain
        uint4 a0 = *(const uint4*)&h_in[(size_t)iv.x * HID + tx * 8];
        uint4 a1 = *(const uint4*)&h_in[(size_t)iv.y * HID + tx * 8];
        uint4 a2 = *(const uint4*)&h_in[(size_t)iv.z * HID + tx * 8];
        uint4 a3 = *(const uint4*)&h_in[(size_t)iv.w * HID + tx * 8];
        acc[0] += bflo(a0.x) + bflo(a1.x) + bflo(a2.x) + bflo(a3.x);
        acc[1] += bfhi(a0.x) + bfhi(a1.x) + bfhi(a2.x) + bfhi(a3.x);
        acc[2] += bflo(a0.y) + bflo(a1.y) + bflo(a2.y) + bflo(a3.y);
        acc[3] += bfhi(a0.y) + bfhi(a1.y) + bfhi(a2.y) + bfhi(a3.y);
        acc[4] += bflo(a0.z) + bflo(a1.z) + bflo(a2.z) + bflo(a3.z);
        acc[5] += bfhi(a0.z) + bfhi(a1.z) + bfhi(a2.z) + bfhi(a3.z);
        acc[6] += bflo(a0.w) + bflo(a1.w) + bflo(a2.w) + bflo(a3.w);
        acc[7] += bfhi(a0.w) + bfhi(a1.w) + bfhi(a2.w) + bfhi(a3.w);
    }
    float hc[8];
    hc[0] = (1.f - ALPHA) * acc[0] + ALPHA * bflo(xq.x);
    hc[1] = (1.f - ALPHA) * acc[1] + ALPHA * bfhi(xq.x);
    hc[2] = (1.f - ALPHA) * acc[2] + ALPHA * bflo(xq.y);
    hc[3] = (1.f - ALPHA) * acc[3] + ALPHA * bfhi(xq.y);
    hc[4] = (1.f - ALPHA) * acc[4] + ALPHA * bflo(xq.z);
    hc[5] = (1.f - ALPHA) * acc[5] + ALPHA * bfhi(xq.z);
    hc[6] = (1.f - ALPHA) * acc[6] + ALPHA * bflo(xq.w);
    hc[7] = (1.f - ALPHA) * acc[7] + ALPHA * bfhi(xq.w);
    {
        uint4 pk;
        pk.x = cvtpk(hc[0], hc[1]);
        pk.y = cvtpk(hc[2], hc[3]);
        pk.z = cvtpk(hc[4], hc[5]);
        pk.w = cvtpk(hc[6], hc[7]);
        *(uint4*)&As[ty][tx * 8] = pk;
    }
    __syncthreads();

    // Phase 2: MFMA conv. wave -> row-tile rt (0..1), col-tile pair (0..2).
    int wave = tid >> 6, lane = tid & 63;
    int quad = lane >> 4, l16 = lane & 15;
    int rt = wave & 1;
    int ct0 = (wave >> 1) * 2, ct1 = ct0 + 1;

    f32x4 g0 = (f32x4){0.f,0.f,0.f,0.f}, g1 = (f32x4){0.f,0.f,0.f,0.f};
#pragma unroll
    for (int ks = 0; ks < 3; ks++) {
        short8 afrag = *(const short8*)&As[rt * 16 + l16][ks * 32 + quad * 8];
        short8 b0 = *(const short8*)&Wc[(size_t)(ct0 * 16 + l16) * HID + ks * 32 + quad * 8];
        short8 b1 = *(const short8*)&Wc[(size_t)(ct1 * 16 + l16) * HID + ks * 32 + quad * 8];
        g0 = __builtin_amdgcn_mfma_f32_16x16x32_bf16(afrag, b0, g0, 0, 0, 0);
        g1 = __builtin_amdgcn_mfma_f32_16x16x32_bf16(afrag, b1, g1, 0, 0, 0);
    }
    float ob = 1.0f - beta;
#pragma unroll
    for (int r = 0; r < 4; r++) {
        int lrow = rt * 16 + quad * 4 + r;
        int nd = snode[lrow];
        if (nd >= 0) {
            int c0 = ct0 * 16 + l16;
            int c1 = ct1 * 16 + l16;
            float v0 = ob * bf2f(As[lrow][c0]) + beta * g0[r];
            float v1 = ob * bf2f(As[lrow][c1]) + beta * g1[r];
            v0 = v0 > 0.f ? v0 : 0.f;
            v1 = v1 > 0.f ? v1 : 0.f;
            h_out[(size_t)nd * HID + c0] = (short)f2bf(v0);
            h_out[(size_t)nd * HID + c1] = (short)f2bf(v1);
        }
    }
}

// ---------------- output GEMM (MFMA bf16) + fused log_softmax ----------------
__global__ __launch_bounds__(256) void out_kernel(
        const short* __restrict__ h_bf, const short* __restrict__ Wt,
        const float* __restrict__ b, float* __restrict__ out) {
    int tid = threadIdx.x;
    int wave = tid >> 6, lane = tid & 63;
    int quad = lane >> 4, l16 = lane & 15;
    int row0 = blockIdx.x * 64 + wave * 16;

    f32x4 acc[4];
#pragma unroll
    for (int n = 0; n < 4; n++) acc[n] = (f32x4){0.f, 0.f, 0.f, 0.f};

    int arow = row0 + l16; if (arow > N_NODES) arow = N_NODES;  // dummy row is zero
#pragma unroll
    for (int ks = 0; ks < 3; ks++) {
        short8 afrag = *(const short8*)&h_bf[(size_t)arow * HID + ks * 32 + quad * 8];
#pragma unroll
        for (int n = 0; n < 4; n++) {
            short8 bfrag = *(const short8*)&Wt[(size_t)(n * 16 + l16) * HID + ks * 32 + quad * 8];
            acc[n] = __builtin_amdgcn_mfma_f32_16x16x32_bf16(afrag, bfrag, acc[n], 0, 0, 0);
        }
    }
#pragma unroll
    for (int n = 0; n < 4; n++) {
        float bias = b[n * 16 + l16];
#pragma unroll
        for (int r = 0; r < 4; r++) acc[n][r] += bias;
    }
#pragma unroll
    for (int r = 0; r < 4; r++) {
        float m = acc[0][r];
        m = fmaxf(m, acc[1][r]); m = fmaxf(m, acc[2][r]); m = fmaxf(m, acc[3][r]);
#pragma unroll
        for (int off = 1; off < 16; off <<= 1) m = fmaxf(m, __shfl_xor(m, off));
        float s = __expf(acc[0][r] - m) + __expf(acc[1][r] - m)
                + __expf(acc[2][r] - m) + __expf(acc[3][r] - m);
#pragma unroll
        for (int off = 1; off < 16; off <<= 1) s += __shfl_xor(s, off);
        float lse = m + __logf(s);
        int grow = row0 + quad * 4 + r;
        if (grow < N_NODES) {
#pragma unroll
            for (int n = 0; n < 4; n++)
                out[(size_t)grow * NCLASS + n * 16 + l16] = acc[n][r] - lse;
        }
    }
}

extern "C" void kernel_launch(void* const* d_in, const int* in_sizes, int n_in,
                              void* d_out, int out_size, void* d_ws, size_t ws_size,
                              hipStream_t stream) {
    const float* x      = (const float*)d_in[0];
    const int*   ei     = (const int*)d_in[1];
    const int*   srcp   = ei;
    const int*   dstp   = ei + N_EDGES;
    const float* W_in   = (const float*)d_in[2];
    const float* b_in   = (const float*)d_in[3];
    const float* conv_W = (const float*)d_in[4];
    const float* W_out  = (const float*)d_in[5];
    const float* b_out  = (const float*)d_in[6];
    float* out = (float*)d_out;

    short* h0  = (short*)d_ws;                               // (N+1) x HID bf16 == x0
    short* h_b = h0  + (size_t)(N_NODES + 1) * HID;
    short* h_c = h_b + (size_t)(N_NODES + 1) * HID;
    short* Wt_in  = h_c + (size_t)(N_NODES + 1) * HID;       // 96 x 512 (fragment-tiled)
    short* Wt_out = Wt_in + (size_t)HID * NFEAT;             // 64 x 96
    short* Wc     = Wt_out + (size_t)NCLASS * HID;           // 8 x 96 x 96 bf16
    // zero-init cluster (one memset): degpack (N) + bkt_cnt (64) u32
    unsigned* degpack = (unsigned*)(Wc + (size_t)NUM_LAYERS * HID * HID);
    int* bkt_cnt    = (int*)(degpack + N_NODES);             // 64 (49 used)
    int* deg        = bkt_cnt + 64;
    int* row_start  = deg + N_NODES;
    int* rsub       = row_start + N_NODES;                   // 3N
    int* blk_sum    = rsub + 3 * N_NODES;
    int* bin_base   = blk_sum + 64;
    int* node_rank  = bin_base + 64;
    int* perm       = node_rank + N_NODES;
    int* blk_bin_cnt= perm + N_NODES;                        // NBB*64
    int* blk_bin_off= blk_bin_cnt + NBB * 64;                // NBB*64
    unsigned* bkt   = (unsigned*)(blk_bin_off + NBB * 64);   // NBKT*BCAP ~ 1.0M u32
    int* csr_src    = (int*)(bkt + (size_t)NBKT * BCAP);     // <= N_EDGES + 3*N_NODES ints

    hipMemsetAsync(degpack, 0, (N_NODES + 64) * sizeof(unsigned), stream);
    hist_kernel<<<(N_EDGES + 255) / 256, 256, 0, stream>>>(srcp, dstp, degpack);
    scan1_kernel<<<NSB, 1024, 0, stream>>>(degpack, deg, row_start, blk_sum);
    scan3_kernel<<<NSB, 1024, 0, stream>>>(row_start, blk_sum, deg, degpack, rsub, csr_src);
    partition_kernel<<<(N_EDGES + 2047) / 2048, 256, 0, stream>>>(srcp, dstp, bkt_cnt, bkt);
    place_kernel<<<NBKT, 256, 0, stream>>>(bkt, bkt_cnt, rsub, csr_src);
    bin_hist2_kernel<<<NBB, 256, 0, stream>>>(deg, node_rank, blk_bin_cnt);
    bin_offsets_kernel<<<1, 64, 0, stream>>>(blk_bin_cnt, blk_bin_off, bin_base);
    bin_place_kernel<<<NBB, 256, 0, stream>>>(deg, node_rank, blk_bin_off, bin_base, perm);

    convert_win_kernel<<<24, 256, 0, stream>>>(W_in, Wt_in);
    convert_wout_kernel<<<NCLASS, HID, 0, stream>>>(W_out, Wt_out, h0, h_b, h_c);
    convert_wconv_kernel<<<dim3(HID, NUM_LAYERS), HID, 0, stream>>>(conv_W, Wc);
    gemm_in_kernel<<<(N_NODES + 63) / 64, 256, 0, stream>>>(x, Wt_in, b_in, h0);

    short* cur = h0;
    short* nxt = h_b;
    for (int l = 0; l < NUM_LAYERS; l++) {
        float beta = logf(0.5f / (float)(l + 1) + 1.0f);
        layer_kernel<<<(N_NODES + 31) / 32, 384, 0, stream>>>(
            cur, h0, row_start, deg, csr_src, perm, Wc + (size_t)l * HID * HID, beta, nxt);
        cur = nxt;
        nxt = (cur == h_b) ? h_c : h_b;
    }

    out_kernel<<<(N_NODES + 63) / 64, 256, 0, stream>>>(cur, Wt_out, b_out, out);
}